// Round 1
// baseline (242.736 us; speedup 1.0000x reference)
//
#include <hip/hip_runtime.h>
#include <math.h>

// sigAct: u = sigmoid(-(lam_b * conv(1-2x))/eps); 5x Jacobi-style updates.
// conv = 17x17 Gaussian (sigma=2), separable -> two 17-tap 1D passes in LDS.
// TAU=0.1, EPS=10, LAMBDA=100, ALPHA=0.5. lam_b = 100*sigmoid(10c) recomputed inline.

#define TILE   64
#define RAD    8
#define MK     17
#define IN_W   80      // TILE + 2*RAD
#define HW     512
#define NIMG   24      // 8*3

template<bool INIT>
__global__ __launch_bounds__(256) void sig_step(
    const float* __restrict__ uin,   // previous u (or x for INIT)
    const float* __restrict__ x,
    const float* __restrict__ c,
    float* __restrict__ uout)
{
    __shared__ float sIn[IN_W * IN_W];    // f = 1-2*uin, with halo, zero-padded
    __shared__ float sTmp[IN_W * TILE];   // after horizontal pass

    const int t    = threadIdx.x;
    const int img  = blockIdx.z;                 // 0..23
    const int row0 = blockIdx.y * TILE;
    const int col0 = blockIdx.x * TILE;
    const size_t ibase = (size_t)img * HW * HW;
    const float* ubase = uin + ibase;

    // 1D normalized Gaussian weights in registers (one-time, trivial cost)
    float g[MK];
    float gsum = 0.f;
#pragma unroll
    for (int i = 0; i < MK; ++i) {
        float d = (float)i - 8.0f;
        g[i] = expf(-d * d * 0.125f);   // 1/(2*sigma^2) = 1/8
        gsum += g[i];
    }
    float ginv = 1.0f / gsum;
#pragma unroll
    for (int i = 0; i < MK; ++i) g[i] *= ginv;

    // ---- load f = 1 - 2*uin into LDS (zero outside image: SAME zero-pad) ----
#pragma unroll
    for (int i = 0; i < (IN_W * IN_W) / 256; ++i) {   // 6400/256 = 25
        int idx = t + i * 256;
        int r  = idx / IN_W;
        int cc = idx - r * IN_W;
        int gr = row0 + r  - RAD;
        int gc = col0 + cc - RAD;
        float v = 0.f;
        if (gr >= 0 && gr < HW && gc >= 0 && gc < HW)
            v = 1.0f - 2.0f * ubase[gr * HW + gc];
        sIn[idx] = v;
    }
    __syncthreads();

    // ---- horizontal 17-tap pass: sTmp[r][c], r in [0,80), c in [0,64) ----
#pragma unroll
    for (int i = 0; i < (IN_W * TILE) / 256; ++i) {   // 5120/256 = 20
        int idx = t + i * 256;
        int r  = idx >> 6;
        int cc = idx & 63;
        const float* row = &sIn[r * IN_W + cc];
        float acc = 0.f;
#pragma unroll
        for (int k = 0; k < MK; ++k) acc += g[k] * row[k];
        sTmp[idx] = acc;
    }
    __syncthreads();

    // ---- vertical 17-tap pass + pointwise update ----
#pragma unroll
    for (int i = 0; i < (TILE * TILE) / 256; ++i) {   // 4096/256 = 16
        int idx = t + i * 256;
        int r  = idx >> 6;
        int cc = idx & 63;
        float acc = 0.f;
        const float* colp = &sTmp[r * TILE + cc];
#pragma unroll
        for (int k = 0; k < MK; ++k) acc += g[k] * colp[k * TILE];

        size_t gidx = ibase + (size_t)(row0 + r) * HW + (col0 + cc);
        float cv = c[gidx];
        float lam_b = 100.0f / (1.0f + expf(-10.0f * cv));   // 100*sigmoid(10c)

        float res;
        if (INIT) {
            // u0 = sigmoid(-(lam_b*v)/10) = 1/(1+exp(lam_b*v*0.1))
            res = 1.0f / (1.0f + expf(lam_b * acc * 0.1f));
        } else {
            // recover u at this pixel from LDS: f = 1-2u -> u = (1-f)/2
            float uprev = 0.5f * (1.0f - sIn[(r + RAD) * IN_W + (cc + RAD)]);
            float xv = x[gidx];
            float tt = (uprev - xv) * 10.0f + lam_b * acc;   // (u-x)/tau + lam_b*v
            float uu = 1.0f / (1.0f + expf(tt * 0.1f));      // sigmoid(-tt/eps)
            res = 0.5f * uprev + 0.5f * uu;                  // alpha = 0.5
        }
        uout[gidx] = res;
    }
}

extern "C" void kernel_launch(void* const* d_in, const int* in_sizes, int n_in,
                              void* d_out, int out_size, void* d_ws, size_t ws_size,
                              hipStream_t stream) {
    const float* x = (const float*)d_in[0];
    const float* c = (const float*)d_in[1];
    float* out = (float*)d_out;
    float* uws = (float*)d_ws;   // one u buffer (25.2 MB)

    dim3 grid(HW / TILE, HW / TILE, NIMG);   // 8 x 8 x 24 = 1536 blocks
    dim3 block(256);

    // init: f = 1-2x, writes u0 -> ws
    sig_step<true ><<<grid, block, 0, stream>>>(x,   x, c, uws);
    // 5 iterations, ping-pong so the last lands in d_out
    sig_step<false><<<grid, block, 0, stream>>>(uws, x, c, out);
    sig_step<false><<<grid, block, 0, stream>>>(out, x, c, uws);
    sig_step<false><<<grid, block, 0, stream>>>(uws, x, c, out);
    sig_step<false><<<grid, block, 0, stream>>>(out, x, c, uws);
    sig_step<false><<<grid, block, 0, stream>>>(uws, x, c, out);
}

// Round 3
// 182.039 us; speedup vs baseline: 1.3334x; 1.3334x over previous
//
#include <hip/hip_runtime.h>
#include <math.h>

// sigAct: u0 = sigmoid(-(lam_b * conv(1-2x))/eps); then 5 damped updates.
// conv = 17x17 Gaussian (sigma=2), separable -> two 17-tap passes in LDS.
// TAU=0.1, EPS=10, LAMBDA=100, ALPHA=0.5. lam_b = 100*sigmoid(10c) inline.
//
// Single 25.6 KB LDS buffer aliased: halo-input tile (80x80) then h-pass
// output (80x64). H-pass: 4 outputs/thread from 5x ds_read_b128.
// V-pass: 1 col x 16 rows/thread, sliding-window in regs.
// u_prev re-read from global (L2/L3-hot) in the epilogue.
// NOTE round-2 bug: symmetric-weight macro was inverted (gs[k] instead of
// gs[|k-8|]) -> inverted Gaussian. Fixed by storing g[17] directly.

#define TILE   64
#define RAD    8
#define IN_W   80      // TILE + 2*RAD
#define HW     512
#define NIMG   24      // 8*3

template<bool INIT>
__global__ __launch_bounds__(256, 4) void sig_step(
    const float* __restrict__ uin,   // previous u (x for INIT)
    const float* __restrict__ x,
    const float* __restrict__ c,
    float* __restrict__ uout)
{
    __shared__ float s[IN_W * IN_W];   // 6400 floats = 25.6 KB, dual-purpose

    const int t    = threadIdx.x;
    const int img  = blockIdx.z;
    const int row0 = blockIdx.y * TILE;
    const int col0 = blockIdx.x * TILE;
    const size_t ibase = (size_t)img * HW * HW;
    const float* ubase = uin + ibase;

    // 1D normalized Gaussian, stored directly: g[k] = exp(-(k-8)^2/8)/S
    float g[17];
    float sum = 0.f;
#pragma unroll
    for (int k = 0; k < 17; ++k) {
        float d = (float)k - 8.f;
        g[k] = expf(-d * d * 0.125f);   // 1/(2*sigma^2) = 1/8
        sum += g[k];
    }
    float inv = 1.f / sum;
#pragma unroll
    for (int k = 0; k < 17; ++k) g[k] *= inv;

    // ---- stage 0: load f = 1-2*uin into s[80][80], zero-padded (SAME) ----
#pragma unroll
    for (int i = 0; i < 7; ++i) {
        int q = t + i * 256;
        if (q < 1600) {                 // 1600 float4 groups = 6400 floats
            int r  = q / 20;
            int cq = (q - r * 20) * 4;
            int gr = row0 + r - RAD;
            int gc = col0 + cq - RAD;
            float4 v;
            if (gr >= 0 && gr < HW && gc >= 0 && gc + 3 < HW) {
                v = *reinterpret_cast<const float4*>(&ubase[gr * HW + gc]);
                v.x = 1.f - 2.f * v.x;  v.y = 1.f - 2.f * v.y;
                v.z = 1.f - 2.f * v.z;  v.w = 1.f - 2.f * v.w;
            } else {
                float tmp[4];
#pragma unroll
                for (int j = 0; j < 4; ++j) {
                    int g2 = gc + j;
                    tmp[j] = (gr >= 0 && gr < HW && g2 >= 0 && g2 < HW)
                               ? 1.f - 2.f * ubase[gr * HW + g2] : 0.f;
                }
                v = make_float4(tmp[0], tmp[1], tmp[2], tmp[3]);
            }
            *reinterpret_cast<float4*>(&s[r * IN_W + cq]) = v;
        }
    }
    __syncthreads();

    // ---- phase 1: horizontal 17-tap into registers (4 outputs/group) ----
    float ph[5][4];
#pragma unroll
    for (int i = 0; i < 5; ++i) {
        int gq = t + i * 256;          // 0..1279 groups (80 rows x 16 grp)
        int r  = gq >> 4;              // row 0..79
        int cg = (gq & 15) * 4;        // col 0,4,..,60
        const float4* p = reinterpret_cast<const float4*>(&s[r * IN_W + cg]);
        float4 a0 = p[0], a1 = p[1], a2 = p[2], a3 = p[3], a4 = p[4];
        float w[20] = { a0.x,a0.y,a0.z,a0.w, a1.x,a1.y,a1.z,a1.w,
                        a2.x,a2.y,a2.z,a2.w, a3.x,a3.y,a3.z,a3.w,
                        a4.x,a4.y,a4.z,a4.w };
#pragma unroll
        for (int j = 0; j < 4; ++j) {
            float acc = 0.f;
#pragma unroll
            for (int k = 0; k < 17; ++k) acc += g[k] * w[j + k];
            ph[i][j] = acc;
        }
    }
    __syncthreads();

    // ---- write h-pass results back into s as tmp[80][64] ----
#pragma unroll
    for (int i = 0; i < 5; ++i) {
        int gq = t + i * 256;
        *reinterpret_cast<float4*>(&s[gq * 4]) =
            make_float4(ph[i][0], ph[i][1], ph[i][2], ph[i][3]);
    }
    __syncthreads();

    // ---- phase 2: vertical 17-tap (1 col x 16 rows/thread) + pointwise ----
    const int cc = t & 63;
    const int rg = t >> 6;             // row group 0..3 (16 rows each)
    float win[32];
#pragma unroll
    for (int j = 0; j < 32; ++j)
        win[j] = s[(rg * 16 + j) * TILE + cc];

#pragma unroll
    for (int m = 0; m < 16; ++m) {
        float acc = 0.f;
#pragma unroll
        for (int k = 0; k < 17; ++k) acc += g[k] * win[m + k];

        int orow = row0 + rg * 16 + m;
        size_t gidx = ibase + (size_t)orow * HW + (col0 + cc);
        float cv = c[gidx];
        float lam = 100.f / (1.f + expf(-10.f * cv));   // 100*sigmoid(10c)
        float res;
        if (INIT) {
            res = 1.f / (1.f + expf(lam * acc * 0.1f)); // sigmoid(-lam*v/eps)
        } else {
            float uprev = uin[gidx];                    // L2/L3-hot re-read
            float xv = x[gidx];
            float tt = (uprev - xv) * 10.f + lam * acc; // (u-x)/tau + lam_b*v
            float uu = 1.f / (1.f + expf(tt * 0.1f));   // sigmoid(-tt/eps)
            res = 0.5f * uprev + 0.5f * uu;             // alpha = 0.5
        }
        uout[gidx] = res;
    }
}

extern "C" void kernel_launch(void* const* d_in, const int* in_sizes, int n_in,
                              void* d_out, int out_size, void* d_ws, size_t ws_size,
                              hipStream_t stream) {
    const float* x = (const float*)d_in[0];
    const float* c = (const float*)d_in[1];
    float* out = (float*)d_out;
    float* uws = (float*)d_ws;   // one u buffer (25.2 MB)

    dim3 grid(HW / TILE, HW / TILE, NIMG);   // 8 x 8 x 24 = 1536 blocks
    dim3 block(256);

    sig_step<true ><<<grid, block, 0, stream>>>(x,   x, c, uws);
    sig_step<false><<<grid, block, 0, stream>>>(uws, x, c, out);
    sig_step<false><<<grid, block, 0, stream>>>(out, x, c, uws);
    sig_step<false><<<grid, block, 0, stream>>>(uws, x, c, out);
    sig_step<false><<<grid, block, 0, stream>>>(out, x, c, uws);
    sig_step<false><<<grid, block, 0, stream>>>(uws, x, c, out);
}

// Round 4
// 152.484 us; speedup vs baseline: 1.5919x; 1.1938x over previous
//
#include <hip/hip_runtime.h>
#include <math.h>

// sigAct: u0 = sigmoid(-(lam_b * conv(1-2x))/eps); then 5 damped updates.
// conv = 17x17 Gaussian (sigma=2), separable -> two 17-tap passes in LDS.
// TAU=0.1, EPS=10, LAMBDA=100, ALPHA=0.5. lam_b = 100*sigmoid(10c) inline.
//
// Round-4: compile-time Gaussian weights (were 17 expf/thread) + fast
// sigmoid via v_rcp(1+__expf(z)) (native v_exp_f32, saturates correctly).
// Structure unchanged: single 25.6 KB aliased LDS buffer, float4 h-pass,
// 16-row sliding-window v-pass, u_prev re-read from global (L2-hot).

#define TILE   64
#define RAD    8
#define IN_W   80      // TILE + 2*RAD
#define HW     512
#define NIMG   24      // 8*3

// 1D normalized Gaussian, sigma=2, 17 taps: exp(-(k-8)^2/8) / 5.0131684
__device__ __constant__ const float GW[17] = {
    6.6916e-05f, 4.3635e-04f, 2.2159612e-03f, 8.7643070e-03f,
    2.6995958e-02f, 6.4759932e-02f, 1.2098751e-01f, 1.7603572e-01f,
    1.9947466e-01f,
    1.7603572e-01f, 1.2098751e-01f, 6.4759932e-02f, 2.6995958e-02f,
    8.7643070e-03f, 2.2159612e-03f, 4.3635e-04f, 6.6916e-05f
};

// sigmoid(-z) = 1/(1+exp(z)); v_rcp_f32 + native exp. inf->0, -inf->1.
__device__ __forceinline__ float inv1pexp(float z) {
    return __builtin_amdgcn_rcpf(1.0f + __expf(z));
}

template<bool INIT>
__global__ __launch_bounds__(256, 4) void sig_step(
    const float* __restrict__ uin,   // previous u (x for INIT)
    const float* __restrict__ x,
    const float* __restrict__ c,
    float* __restrict__ uout)
{
    __shared__ float s[IN_W * IN_W];   // 6400 floats = 25.6 KB, dual-purpose

    const int t    = threadIdx.x;
    const int img  = blockIdx.z;
    const int row0 = blockIdx.y * TILE;
    const int col0 = blockIdx.x * TILE;
    const size_t ibase = (size_t)img * HW * HW;
    const float* ubase = uin + ibase;

    // ---- stage 0: load f = 1-2*uin into s[80][80], zero-padded (SAME) ----
#pragma unroll
    for (int i = 0; i < 7; ++i) {
        int q = t + i * 256;
        if (q < 1600) {                 // 1600 float4 groups = 6400 floats
            int r  = q / 20;
            int cq = (q - r * 20) * 4;
            int gr = row0 + r - RAD;
            int gc = col0 + cq - RAD;
            float4 v;
            if (gr >= 0 && gr < HW && gc >= 0 && gc + 3 < HW) {
                v = *reinterpret_cast<const float4*>(&ubase[gr * HW + gc]);
                v.x = 1.f - 2.f * v.x;  v.y = 1.f - 2.f * v.y;
                v.z = 1.f - 2.f * v.z;  v.w = 1.f - 2.f * v.w;
            } else {
                float tmp[4];
#pragma unroll
                for (int j = 0; j < 4; ++j) {
                    int g2 = gc + j;
                    tmp[j] = (gr >= 0 && gr < HW && g2 >= 0 && g2 < HW)
                               ? 1.f - 2.f * ubase[gr * HW + g2] : 0.f;
                }
                v = make_float4(tmp[0], tmp[1], tmp[2], tmp[3]);
            }
            *reinterpret_cast<float4*>(&s[r * IN_W + cq]) = v;
        }
    }
    __syncthreads();

    // ---- phase 1: horizontal 17-tap into registers (4 outputs/group) ----
    float ph[5][4];
#pragma unroll
    for (int i = 0; i < 5; ++i) {
        int gq = t + i * 256;          // 0..1279 groups (80 rows x 16 grp)
        int r  = gq >> 4;              // row 0..79
        int cg = (gq & 15) * 4;        // col 0,4,..,60
        const float4* p = reinterpret_cast<const float4*>(&s[r * IN_W + cg]);
        float4 a0 = p[0], a1 = p[1], a2 = p[2], a3 = p[3], a4 = p[4];
        float w[20] = { a0.x,a0.y,a0.z,a0.w, a1.x,a1.y,a1.z,a1.w,
                        a2.x,a2.y,a2.z,a2.w, a3.x,a3.y,a3.z,a3.w,
                        a4.x,a4.y,a4.z,a4.w };
#pragma unroll
        for (int j = 0; j < 4; ++j) {
            float acc = 0.f;
#pragma unroll
            for (int k = 0; k < 17; ++k) acc += GW[k] * w[j + k];
            ph[i][j] = acc;
        }
    }
    __syncthreads();

    // ---- write h-pass results back into s as tmp[80][64] ----
#pragma unroll
    for (int i = 0; i < 5; ++i) {
        int gq = t + i * 256;
        *reinterpret_cast<float4*>(&s[gq * 4]) =
            make_float4(ph[i][0], ph[i][1], ph[i][2], ph[i][3]);
    }
    __syncthreads();

    // ---- phase 2: vertical 17-tap (1 col x 16 rows/thread) + pointwise ----
    const int cc = t & 63;
    const int rg = t >> 6;             // row group 0..3 (16 rows each)
    float win[32];
#pragma unroll
    for (int j = 0; j < 32; ++j)
        win[j] = s[(rg * 16 + j) * TILE + cc];

#pragma unroll
    for (int m = 0; m < 16; ++m) {
        float acc = 0.f;
#pragma unroll
        for (int k = 0; k < 17; ++k) acc += GW[k] * win[m + k];

        int orow = row0 + rg * 16 + m;
        size_t gidx = ibase + (size_t)orow * HW + (col0 + cc);
        float cv = c[gidx];
        float lam = 100.f * inv1pexp(-10.f * cv);       // 100*sigmoid(10c)
        float res;
        if (INIT) {
            res = inv1pexp(lam * acc * 0.1f);           // sigmoid(-lam*v/eps)
        } else {
            float uprev = uin[gidx];                    // L2/L3-hot re-read
            float xv = x[gidx];
            float tt = (uprev - xv) * 10.f + lam * acc; // (u-x)/tau + lam_b*v
            float uu = inv1pexp(tt * 0.1f);             // sigmoid(-tt/eps)
            res = 0.5f * uprev + 0.5f * uu;             // alpha = 0.5
        }
        uout[gidx] = res;
    }
}

extern "C" void kernel_launch(void* const* d_in, const int* in_sizes, int n_in,
                              void* d_out, int out_size, void* d_ws, size_t ws_size,
                              hipStream_t stream) {
    const float* x = (const float*)d_in[0];
    const float* c = (const float*)d_in[1];
    float* out = (float*)d_out;
    float* uws = (float*)d_ws;   // one u buffer (25.2 MB)

    dim3 grid(HW / TILE, HW / TILE, NIMG);   // 8 x 8 x 24 = 1536 blocks
    dim3 block(256);

    sig_step<true ><<<grid, block, 0, stream>>>(x,   x, c, uws);
    sig_step<false><<<grid, block, 0, stream>>>(uws, x, c, out);
    sig_step<false><<<grid, block, 0, stream>>>(out, x, c, uws);
    sig_step<false><<<grid, block, 0, stream>>>(uws, x, c, out);
    sig_step<false><<<grid, block, 0, stream>>>(out, x, c, uws);
    sig_step<false><<<grid, block, 0, stream>>>(uws, x, c, out);
}

// Round 5
// 127.589 us; speedup vs baseline: 1.9025x; 1.1951x over previous
//
#include <hip/hip_runtime.h>
#include <hip/hip_fp16.h>
#include <math.h>

// sigAct: u0 = sigmoid(-(lam_b*conv(1-2x))/eps); 5 damped updates.
// conv = separable 17-tap Gaussian (sigma=2) in LDS, f32 accumulation.
// Round-5: fp16 u ping-pong + fp16 LDS (23KB, de-aliased, 2 barriers),
// packed half2 xl=(x,lam) precomputed by INIT, __launch_bounds__(256,6)
// -> 6 blocks/CU (75% occupancy). Epilogue u_prev comes from LDS.

#define TILE 64
#define RAD  8
#define IN_W 80
#define HW   512
#define NIMG 24
#define NPIX ((size_t)HW * HW * NIMG)

// 1D normalized Gaussian, sigma=2, 17 taps: exp(-(k-8)^2/8) / 5.0131684
__device__ __constant__ const float GWc[17] = {
    6.6916e-05f, 4.3635e-04f, 2.2159612e-03f, 8.7643070e-03f,
    2.6995958e-02f, 6.4759932e-02f, 1.2098751e-01f, 1.7603572e-01f,
    1.9947466e-01f,
    1.7603572e-01f, 1.2098751e-01f, 6.4759932e-02f, 2.6995958e-02f,
    8.7643070e-03f, 2.2159612e-03f, 4.3635e-04f, 6.6916e-05f
};

struct alignas(8)  H4 { __half2 a, b; };
struct alignas(16) H8 { __half2 a, b, c, d; };

// sigmoid(-z) = 1/(1+exp(z)); inf->0, -inf->1.
__device__ __forceinline__ float inv1pexp(float z) {
    return __builtin_amdgcn_rcpf(1.0f + __expf(z));
}

template<int MODE> // 0=INIT 1=MID 2=FINAL
__global__ __launch_bounds__(256, 6) void sig_step(
    const __half* __restrict__ uin,   // MID/FINAL: previous u (half)
    const float*  __restrict__ xg,    // INIT only
    const float*  __restrict__ cgl,   // INIT only
    __half2* xl,                      // (x, lam) packed; INIT writes, else reads
    void* uout)                       // half (INIT/MID) or float (FINAL)
{
    __shared__ __half sIn [IN_W * IN_W];   // f = 1-2u, halo tile (12.8 KB)
    __shared__ __half sTmp[IN_W * TILE];   // h-pass output      (10.2 KB)

    const int t    = threadIdx.x;
    const int img  = blockIdx.z;
    const int row0 = blockIdx.y * TILE;
    const int col0 = blockIdx.x * TILE;
    const size_t ibase = (size_t)img * HW * HW;

    // ---- stage 0: load f = 1-2*u into sIn[80][80], zero-padded (SAME) ----
    if constexpr (MODE == 0) {
        const float* xb = xg + ibase;
#pragma unroll
        for (int i = 0; i < 7; ++i) {
            int q = t + i * 256;
            if (q < 1600) {                    // 1600 float4 chunks
                int r  = q / 20;
                int c4 = (q - r * 20) * 4;
                int gr = row0 + r - RAD;
                int gc = col0 + c4 - RAD;      // mult of 4 -> chunk fully in/out
                H4 o;
                if (gr >= 0 && gr < HW && gc >= 0 && gc < HW) {
                    float4 v = *reinterpret_cast<const float4*>(&xb[(size_t)gr * HW + gc]);
                    o.a = __floats2half2_rn(1.f - 2.f * v.x, 1.f - 2.f * v.y);
                    o.b = __floats2half2_rn(1.f - 2.f * v.z, 1.f - 2.f * v.w);
                } else {
                    o.a = __floats2half2_rn(0.f, 0.f); o.b = o.a;
                }
                *reinterpret_cast<H4*>(&sIn[r * IN_W + c4]) = o;
            }
        }
    } else {
        const __half* ub = uin + ibase;
#pragma unroll
        for (int i = 0; i < 4; ++i) {
            int q = t + i * 256;
            if (q < 800) {                     // 800 x 16B chunks (8 halfs)
                int r  = q / 10;
                int c8 = (q - r * 10) * 8;
                int gr = row0 + r - RAD;
                int gc = col0 + c8 - RAD;      // mult of 8 -> chunk fully in/out
                H8 v;
                if (gr >= 0 && gr < HW && gc >= 0 && gc < HW) {
                    v = *reinterpret_cast<const H8*>(&ub[(size_t)gr * HW + gc]);
                    const __half2 one2 = __floats2half2_rn(1.f, 1.f);
                    v.a = __hsub2(one2, __hadd2(v.a, v.a));
                    v.b = __hsub2(one2, __hadd2(v.b, v.b));
                    v.c = __hsub2(one2, __hadd2(v.c, v.c));
                    v.d = __hsub2(one2, __hadd2(v.d, v.d));
                } else {
                    v.a = __floats2half2_rn(0.f, 0.f);
                    v.b = v.a; v.c = v.a; v.d = v.a;
                }
                *reinterpret_cast<H8*>(&sIn[r * IN_W + c8]) = v;
            }
        }
    }
    __syncthreads();

    // ---- phase 1: horizontal 17-tap, f32 accum, write half to sTmp ----
#pragma unroll
    for (int i = 0; i < 5; ++i) {
        int gq = t + i * 256;              // 1280 groups: 80 rows x 16
        int r  = gq >> 4;
        int cp = (gq & 15) * 4;
        const __half* wp = &sIn[r * IN_W + cp];
        float w[20];
#pragma unroll
        for (int j = 0; j < 5; ++j) {      // 5 x ds_read_b64
            H4 h = *reinterpret_cast<const H4*>(wp + j * 4);
            float2 f0 = __half22float2(h.a);
            float2 f1 = __half22float2(h.b);
            w[j*4+0] = f0.x; w[j*4+1] = f0.y;
            w[j*4+2] = f1.x; w[j*4+3] = f1.y;
        }
        float a0 = 0.f, a1 = 0.f, a2 = 0.f, a3 = 0.f;
#pragma unroll
        for (int k = 0; k < 17; ++k) {
            float g = GWc[k];
            a0 += g * w[k];     a1 += g * w[k + 1];
            a2 += g * w[k + 2]; a3 += g * w[k + 3];
        }
        H4 o; o.a = __floats2half2_rn(a0, a1); o.b = __floats2half2_rn(a2, a3);
        *reinterpret_cast<H4*>(&sTmp[r * TILE + cp]) = o;
    }
    __syncthreads();

    // ---- phase 2: vertical 17-tap (1 col x 16 rows/thread) + pointwise ----
    const int cc = t & 63;
    const int rg = t >> 6;
    const size_t pbase = ibase + (size_t)(row0 + rg * 16) * HW + (col0 + cc);

    __half2 xlp[16];
    if constexpr (MODE == 2) {     // preload: xl may alias uout (d_out)
#pragma unroll
        for (int m = 0; m < 16; ++m) xlp[m] = xl[pbase + (size_t)m * HW];
    }

    float win[32];
#pragma unroll
    for (int j = 0; j < 32; ++j)
        win[j] = __half2float(sTmp[(rg * 16 + j) * TILE + cc]);

#pragma unroll
    for (int m = 0; m < 16; ++m) {
        float acc = 0.f;
#pragma unroll
        for (int k = 0; k < 17; ++k) acc += GWc[k] * win[m + k];

        size_t gidx = pbase + (size_t)m * HW;
        if constexpr (MODE == 0) {
            float xv  = xg[gidx];
            float lam = 100.f * inv1pexp(-10.f * cgl[gidx]);
            float res = inv1pexp(lam * acc * 0.1f);      // sigmoid(-lam*v/eps)
            xl[gidx] = __floats2half2_rn(xv, lam);
            ((__half*)uout)[gidx] = __float2half(res);
        } else {
            float xv, lam;
            if constexpr (MODE == 2) {
                float2 p = __half22float2(xlp[m]); xv = p.x; lam = p.y;
            } else {
                float2 p = __half22float2(xl[gidx]); xv = p.x; lam = p.y;
            }
            float uprev = 0.5f * (1.f -
                __half2float(sIn[(rg * 16 + m + RAD) * IN_W + (cc + RAD)]));
            float tt = (uprev - xv) * 10.f + lam * acc;  // (u-x)/tau + lam*v
            float uu = inv1pexp(tt * 0.1f);              // sigmoid(-tt/eps)
            float res = 0.5f * uprev + 0.5f * uu;        // alpha = 0.5
            if constexpr (MODE == 2) ((float*)uout)[gidx] = res;
            else                     ((__half*)uout)[gidx] = __float2half(res);
        }
    }
}

extern "C" void kernel_launch(void* const* d_in, const int* in_sizes, int n_in,
                              void* d_out, int out_size, void* d_ws, size_t ws_size,
                              hipStream_t stream) {
    const float* x = (const float*)d_in[0];
    const float* c = (const float*)d_in[1];

    __half* u0 = (__half*)d_ws;          // NPIX halfs = 12.6 MB
    __half* u1 = u0 + NPIX;              // 12.6 MB
    __half2* xl;
    if (ws_size >= NPIX * 8)             // u0+u1 (4B/px) + xl (4B/px)
        xl = (__half2*)((char*)d_ws + NPIX * 4);
    else
        xl = (__half2*)d_out;            // safe: FINAL preloads before storing

    dim3 grid(HW / TILE, HW / TILE, NIMG);   // 8 x 8 x 24
    dim3 block(256);

    sig_step<0><<<grid, block, 0, stream>>>(nullptr, x, c, xl, u0);
    sig_step<1><<<grid, block, 0, stream>>>(u0, x, c, xl, u1);
    sig_step<1><<<grid, block, 0, stream>>>(u1, x, c, xl, u0);
    sig_step<1><<<grid, block, 0, stream>>>(u0, x, c, xl, u1);
    sig_step<1><<<grid, block, 0, stream>>>(u1, x, c, xl, u0);
    sig_step<2><<<grid, block, 0, stream>>>(u0, x, c, xl, d_out);
}